// Round 10
// baseline (313.660 us; speedup 1.0000x reference)
//
#include <hip/hip_runtime.h>
#include <hip/hip_bf16.h>
#include <stdint.h>

#define BATCH 8
#define SEQ   2048
#define DIM   1024

typedef unsigned short u16;
typedef __attribute__((ext_vector_type(8))) short short8;
typedef __attribute__((ext_vector_type(4))) float f32x4;
typedef __attribute__((ext_vector_type(4))) unsigned short us4;

__device__ __forceinline__ u16 f2bf(float x){
  union { float f; uint32_t u; } c; c.f = x;
  uint32_t u = c.u;
  uint32_t r = u + 0x7fffu + ((u >> 16) & 1u);
  return (u16)(r >> 16);
}
__device__ __forceinline__ float bf2f(u16 s){
  union { uint32_t u; float f; } c; c.u = ((uint32_t)s) << 16;
  return c.f;
}

__device__ __forceinline__ void gload16(const void* g, void* l){
  __builtin_amdgcn_global_load_lds(
      (const __attribute__((address_space(1))) void*)g,
      (__attribute__((address_space(3))) void*)l, 16, 0, 0);
}

// ---------- split fp32 [R][1024] -> u16 [R][2048] rows packed [hi|lo] ----------
__global__ __launch_bounds__(256) void k_split(const float* __restrict__ src,
                                               u16* __restrict__ dst, int nchunk){
  for (int i = blockIdx.x*blockDim.x + threadIdx.x; i < nchunk; i += gridDim.x*blockDim.x){
    int r = i >> 8;
    int c = (i & 255) << 2;
    f32x4 v = *(const f32x4*)(src + (size_t)r*DIM + c);
    us4 h, l;
    #pragma unroll
    for (int j = 0; j < 4; j++){
      u16 hh = f2bf(v[j]);
      h[j] = hh;
      l[j] = f2bf(v[j] - bf2f(hh));
    }
    u16* d = dst + (size_t)r*(2*DIM) + c;
    *(us4*)d         = h;
    *(us4*)(d + DIM) = l;
  }
}

// ---------- transpose + split (K and V in one launch): z<8 -> K->Kt, z>=8 -> V->Vt ----------
__global__ __launch_bounds__(256) void k_convert_kv(const float* __restrict__ K,
                                                    const float* __restrict__ V,
                                                    u16* __restrict__ Kt,
                                                    u16* __restrict__ Vt){
  __shared__ float tile[64][65];
  int z = blockIdx.z;
  const float* Src = (z < 8 ? K : V);
  u16* Dst = (z < 8 ? Kt : Vt);
  int zb = z & 7;
  const float* Vb = Src + (size_t)zb * SEQ * DIM;
  u16* Vtb = Dst + (size_t)zb * DIM * (2*SEQ);
  int s0 = blockIdx.x * 64, d0 = blockIdx.y * 64;
  int t = threadIdx.x;
  int rs = t >> 4;
  int cd = (t & 15) * 4;
  #pragma unroll
  for (int i = 0; i < 4; i++){
    int s = rs + i*16;
    f32x4 v = *(const f32x4*)(Vb + (size_t)(s0 + s)*DIM + d0 + cd);
    tile[s][cd+0] = v[0]; tile[s][cd+1] = v[1];
    tile[s][cd+2] = v[2]; tile[s][cd+3] = v[3];
  }
  __syncthreads();
  int dl = t >> 4;
  int sl = (t & 15) * 4;
  #pragma unroll
  for (int i = 0; i < 4; i++){
    int d = dl + i*16;
    us4 h, l;
    #pragma unroll
    for (int j = 0; j < 4; j++){
      float x = tile[sl+j][d];
      u16 hh = f2bf(x);
      h[j] = hh;
      l[j] = f2bf(x - bf2f(hh));
    }
    size_t off = (size_t)(d0 + d) * (2*SEQ) + s0 + sl;
    *(us4*)(Vtb + off)       = h;
    *(us4*)(Vtb + off + SEQ) = l;
  }
}

// ---------- 128x128 4-wave GEMM, hi/lo split, single-buffer, 4 blocks/CU ----------
// Mechanism: cross-block TLP (4 co-resident blocks per CU at different loop
// phases hide each other's stage-wait and LDS bursts). Simple 2-barrier loop.
// A: [M][2*KROW] u16 [hi|lo]; B: [Nrows][2*KROW].
// SPLITK=1: z -> (kh=z>>3, zb=z&7), contracts K=1024 at offset kh*1024.
// SPLITOUT=1: C = acc/32 split u16 [M][2*NOUT]; SPLITOUT=0: C = acc fp32 [M][NOUT].
template<int KROW, int SPLITK, int SPLITOUT, int NOUT, int TX, int TY>
__global__ __launch_bounds__(256,4) void k_gemmS(const u16* __restrict__ A,
                                                 const u16* __restrict__ B,
                                                 void* __restrict__ Cout,
                                                 size_t aStride, size_t bStride, size_t cStride){
  constexpr int LA = 2*KROW;
  constexpr int ITER = (SPLITK ? 1024 : KROW) / 32;
  __shared__ __align__(16) u16 lds[4][128*32];   // Ah, Al, Bh, Bl = 32 KB

  int xcd = blockIdx.x & 7;
  int idx = blockIdx.x >> 3;
  int nPerX = gridDim.x >> 3;
  int gid = xcd * nPerX + idx;
  constexpr int TPZ = TX*TY;
  int z  = gid / TPZ;
  int rm = gid % TPZ;
  int bx = rm % TX;
  int by = rm / TX;

  int zb = SPLITK ? (z & 7) : z;
  int kh = SPLITK ? (z >> 3) : 0;

  const u16* Ab = A + (size_t)zb * aStride + (size_t)kh * 1024;
  const u16* Bb = B + (size_t)zb * bStride + (size_t)kh * 1024;

  int t = threadIdx.x, lane = t & 63, w = t >> 6;
  int wm = (w & 1) * 64, wn = (w >> 1) * 64;
  int fr = lane & 15;

  // staging: chunk c = w*2+o covers rows [c*16, c*16+16); lane -> row c*16+(lane>>2),
  // LDS slot (lane&3) linear; fetches pre-swizzled global slot (lane&3)^((lane>>3)&3).
  int srow    = lane >> 2;
  int srcSlot = ((lane & 3) ^ ((lane >> 3) & 3)) * 8;

  const u16* aBase = Ab + ((size_t)bx*128) * LA + srcSlot;
  const u16* bBase = Bb + ((size_t)by*128) * LA + srcSlot;

  // fragment read: global slot (lane>>4) at row r -> LDS slot (lane>>4)^((r>>1)&3)
  int rdSlot = (((lane >> 4) ^ ((fr >> 1) & 3))) * 8;

  f32x4 acc[4][4] = {};

  for (int ti = 0; ti < ITER; ti++){
    size_t kof = (size_t)ti * 32;
    #pragma unroll
    for (int o = 0; o < 2; o++){
      int c = w*2 + o;
      size_t ro = (size_t)(c*16 + srow) * LA + kof;
      const u16* ga = aBase + ro;
      const u16* gb = bBase + ro;
      int le = c * 512;
      gload16(ga,        &lds[0][le]);
      gload16(ga + KROW, &lds[1][le]);
      gload16(gb,        &lds[2][le]);
      gload16(gb + KROW, &lds[3][le]);
    }
    __syncthreads();

    short8 fah[4], fal[4], fbh[4], fbl[4];
    #pragma unroll
    for (int mi = 0; mi < 4; mi++){
      fah[mi] = *(const short8*)&lds[0][(wm + mi*16 + fr)*32 + rdSlot];
      fal[mi] = *(const short8*)&lds[1][(wm + mi*16 + fr)*32 + rdSlot];
      fbh[mi] = *(const short8*)&lds[2][(wn + mi*16 + fr)*32 + rdSlot];
      fbl[mi] = *(const short8*)&lds[3][(wn + mi*16 + fr)*32 + rdSlot];
    }
    #pragma unroll
    for (int mi = 0; mi < 4; mi++){
      #pragma unroll
      for (int ni = 0; ni < 4; ni++){
        acc[mi][ni] = __builtin_amdgcn_mfma_f32_16x16x32_bf16(fah[mi], fbh[ni], acc[mi][ni], 0,0,0);
        acc[mi][ni] = __builtin_amdgcn_mfma_f32_16x16x32_bf16(fah[mi], fbl[ni], acc[mi][ni], 0,0,0);
        acc[mi][ni] = __builtin_amdgcn_mfma_f32_16x16x32_bf16(fal[mi], fbh[ni], acc[mi][ni], 0,0,0);
      }
    }
    __syncthreads();
  }

  int cr = (lane >> 4) * 4, cc = lane & 15;
  if (SPLITOUT){
    u16* Cb = (u16*)Cout + (size_t)z * cStride;
    const float scale = 0.03125f;   // 1/sqrt(1024)
    #pragma unroll
    for (int mi = 0; mi < 4; mi++){
      int gr = bx*128 + wm + mi*16 + cr;
      #pragma unroll
      for (int ni = 0; ni < 4; ni++){
        int gc = by*128 + wn + ni*16 + cc;
        #pragma unroll
        for (int rr = 0; rr < 4; rr++){
          float x = acc[mi][ni][rr] * scale;
          u16 h = f2bf(x);
          u16 l = f2bf(x - bf2f(h));
          size_t off = (size_t)(gr + rr) * (2*NOUT) + gc;
          Cb[off]        = h;
          Cb[off + NOUT] = l;
        }
      }
    }
  } else {
    float* Cb = (float*)Cout + (size_t)z * cStride;
    #pragma unroll
    for (int mi = 0; mi < 4; mi++){
      int gr = bx*128 + wm + mi*16 + cr;
      #pragma unroll
      for (int ni = 0; ni < 4; ni++){
        int gc = by*128 + wn + ni*16 + cc;
        #pragma unroll
        for (int rr = 0; rr < 4; rr++){
          Cb[(size_t)(gr + rr) * NOUT + gc] = acc[mi][ni][rr];
        }
      }
    }
  }
}

// ---------- reduce split-K partials + scale + split to u16 [hi|lo] ----------
__global__ __launch_bounds__(256) void k_reduce_split(const float* __restrict__ P,
                                                      u16* __restrict__ Ws){
  int i = blockIdx.x*256 + threadIdx.x;
  int rg = i >> 8;                 // zb*1024 + d, 8192 rows (kh=0 half)
  int c  = (i & 255) * 4;
  f32x4 a = *(const f32x4*)(P + (size_t)rg*1024 + c);
  f32x4 b = *(const f32x4*)(P + ((size_t)rg + 8192)*1024 + c);
  us4 h, l;
  #pragma unroll
  for (int j = 0; j < 4; j++){
    float x = (a[j] + b[j]) * 0.03125f;
    u16 hh = f2bf(x);
    h[j] = hh;
    l[j] = f2bf(x - bf2f(hh));
  }
  int zb = rg >> 10, d = rg & 1023;
  u16* Wb = Ws + (size_t)zb * ((size_t)DIM * 2*DIM);
  *(us4*)(Wb + (size_t)d*2048 + c)        = h;
  *(us4*)(Wb + (size_t)d*2048 + 1024 + c) = l;
}

// ---------- row softmax over D=1024, in place on d_out ----------
__global__ __launch_bounds__(256) void k_softmax(float* __restrict__ O){
  float* p = O + (size_t)blockIdx.x * DIM;
  int t = threadIdx.x;
  int lane = t & 63, wave = t >> 6;
  f32x4 v = *(f32x4*)(p + t*4);
  float m = fmaxf(fmaxf(v[0], v[1]), fmaxf(v[2], v[3]));
  #pragma unroll
  for (int o = 32; o > 0; o >>= 1) m = fmaxf(m, __shfl_xor(m, o));
  __shared__ float rmax[4], rsum[4];
  if (lane == 0) rmax[wave] = m;
  __syncthreads();
  m = fmaxf(fmaxf(rmax[0], rmax[1]), fmaxf(rmax[2], rmax[3]));
  float e0 = expf(v[0]-m), e1 = expf(v[1]-m), e2 = expf(v[2]-m), e3 = expf(v[3]-m);
  float s = e0 + e1 + e2 + e3;
  #pragma unroll
  for (int o = 32; o > 0; o >>= 1) s += __shfl_xor(s, o);
  if (lane == 0) rsum[wave] = s;
  __syncthreads();
  s = rsum[0] + rsum[1] + rsum[2] + rsum[3];
  float inv = 1.0f / s;
  f32x4 rv = { e0*inv, e1*inv, e2*inv, e3*inv };
  *(f32x4*)(p + t*4) = rv;
}

extern "C" void kernel_launch(void* const* d_in, const int* in_sizes, int n_in,
                              void* d_out, int out_size, void* d_ws, size_t ws_size,
                              hipStream_t stream){
  const float* Q = (const float*)d_in[0];
  const float* K = (const float*)d_in[1];
  const float* V = (const float*)d_in[2];
  float* Out = (float*)d_out;
  u16* w = (u16*)d_ws;

  const size_t QsB = (size_t)SEQ * (2*DIM);
  const size_t KtB = (size_t)DIM * (2*SEQ);
  const size_t VtB = KtB;
  const size_t WsB = (size_t)DIM * (2*DIM);

  dim3 blk(256);
  dim3 cgrid(SEQ/64, DIM/64, 16);

  const size_t base2 = 8 * (KtB + VtB + WsB) * sizeof(u16);          // ~167.8 MB
  const size_t needA = base2 + (size_t)16*1024*1024*sizeof(float);   // ~234.9 MB
  const size_t needB = base2;

  if (ws_size >= needA){
    u16* Kt = w;
    u16* Vt = Kt + 8*KtB;
    u16* Ws = Vt + 8*VtB;
    float* Part = (float*)(Ws + 8*WsB);
    u16* Qs = w;                         // reuses Kt/Vt region after GEMM-A (stream-ordered)
    k_convert_kv<<<cgrid, blk, 0, stream>>>(K, V, Kt, Vt);
    // GEMM-A split-K x2: Part[z=kh*8+zb] = Vt_zb . Kt_zb^T |_khalf (fp32). 1024 blocks.
    k_gemmS<SEQ, 1, 0, DIM, 8, 8><<<dim3(1024), blk, 0, stream>>>(
        Vt, Kt, Part, VtB, KtB, (size_t)1024*1024);
    k_reduce_split<<<dim3(8192), blk, 0, stream>>>(Part, Ws);
    k_split<<<dim3(2048), blk, 0, stream>>>(Q, Qs, 8*SEQ*(DIM/4));
    // GEMM-B: Out = Qs . Ws^T (fp32). 1024 blocks, 1 batch per XCD.
    k_gemmS<DIM, 0, 0, DIM, 16, 8><<<dim3(1024), blk, 0, stream>>>(
        Qs, Ws, Out, QsB, WsB, (size_t)SEQ*DIM);
  } else if (ws_size >= needB){
    u16* Kt = w;
    u16* Vt = Kt + 8*KtB;
    u16* Ws = Vt + 8*VtB;
    u16* Qs = w;
    k_convert_kv<<<cgrid, blk, 0, stream>>>(K, V, Kt, Vt);
    // GEMM-A full-K in-block, u16 split out. 512 blocks (2/CU).
    k_gemmS<SEQ, 0, 1, DIM, 8, 8><<<dim3(512), blk, 0, stream>>>(
        Vt, Kt, Ws, VtB, KtB, WsB);
    k_split<<<dim3(2048), blk, 0, stream>>>(Q, Qs, 8*SEQ*(DIM/4));
    k_gemmS<DIM, 0, 0, DIM, 16, 8><<<dim3(1024), blk, 0, stream>>>(
        Qs, Ws, Out, QsB, WsB, (size_t)SEQ*DIM);
  } else {
    // per-batch fallback
    u16* Qs = w;
    u16* Kt = Qs + QsB;
    u16* Vt = Kt + KtB;
    u16* Ws = Vt + VtB;
    for (int b = 0; b < BATCH; b++){
      const size_t inOff = (size_t)b * SEQ * DIM;
      k_split<<<dim3(1024), blk, 0, stream>>>(Q + inOff, Qs, SEQ*(DIM/4));
      k_convert_kv<<<dim3(SEQ/64, DIM/64, 1), blk, 0, stream>>>(K + inOff, K + inOff, Kt, Kt);
      k_convert_kv<<<dim3(SEQ/64, DIM/64, 1), blk, 0, stream>>>(V + inOff, V + inOff, Vt, Vt);
      k_gemmS<SEQ, 0, 1, DIM, 8, 8><<<dim3(64), blk, 0, stream>>>(
          Vt, Kt, Ws, VtB, KtB, WsB);
      k_gemmS<DIM, 0, 0, DIM, 16, 8><<<dim3(128), blk, 0, stream>>>(
          Qs, Ws, Out + inOff, QsB, WsB, (size_t)SEQ*DIM);
    }
  }
  k_softmax<<<dim3(BATCH*SEQ), blk, 0, stream>>>(Out);
}

// Round 11
// 297.231 us; speedup vs baseline: 1.0553x; 1.0553x over previous
//
#include <hip/hip_runtime.h>
#include <hip/hip_bf16.h>
#include <stdint.h>

#define BATCH 8
#define SEQ   2048
#define DIM   1024

typedef unsigned short u16;
typedef __attribute__((ext_vector_type(8))) short short8;
typedef __attribute__((ext_vector_type(4))) float f32x4;
typedef __attribute__((ext_vector_type(4))) unsigned short us4;

__device__ __forceinline__ u16 f2bf(float x){
  union { float f; uint32_t u; } c; c.f = x;
  uint32_t u = c.u;
  uint32_t r = u + 0x7fffu + ((u >> 16) & 1u);
  return (u16)(r >> 16);
}
__device__ __forceinline__ float bf2f(u16 s){
  union { uint32_t u; float f; } c; c.u = ((uint32_t)s) << 16;
  return c.f;
}

__device__ __forceinline__ void gload16(const void* g, void* l){
  __builtin_amdgcn_global_load_lds(
      (const __attribute__((address_space(1))) void*)g,
      (__attribute__((address_space(3))) void*)l, 16, 0, 0);
}

// ---------- split fp32 [R][1024] -> u16 [R][2048] rows packed [hi|lo] ----------
__global__ __launch_bounds__(256) void k_split(const float* __restrict__ src,
                                               u16* __restrict__ dst, int nchunk){
  for (int i = blockIdx.x*blockDim.x + threadIdx.x; i < nchunk; i += gridDim.x*blockDim.x){
    int r = i >> 8;
    int c = (i & 255) << 2;
    f32x4 v = *(const f32x4*)(src + (size_t)r*DIM + c);
    us4 h, l;
    #pragma unroll
    for (int j = 0; j < 4; j++){
      u16 hh = f2bf(v[j]);
      h[j] = hh;
      l[j] = f2bf(v[j] - bf2f(hh));
    }
    u16* d = dst + (size_t)r*(2*DIM) + c;
    *(us4*)d         = h;
    *(us4*)(d + DIM) = l;
  }
}

// ---------- transpose + split (K and V in one launch): z<8 -> K->Kt, z>=8 -> V->Vt ----------
__global__ __launch_bounds__(256) void k_convert_kv(const float* __restrict__ K,
                                                    const float* __restrict__ V,
                                                    u16* __restrict__ Kt,
                                                    u16* __restrict__ Vt){
  __shared__ float tile[64][65];
  int z = blockIdx.z;
  const float* Src = (z < 8 ? K : V);
  u16* Dst = (z < 8 ? Kt : Vt);
  int zb = z & 7;
  const float* Vb = Src + (size_t)zb * SEQ * DIM;
  u16* Vtb = Dst + (size_t)zb * DIM * (2*SEQ);
  int s0 = blockIdx.x * 64, d0 = blockIdx.y * 64;
  int t = threadIdx.x;
  int rs = t >> 4;
  int cd = (t & 15) * 4;
  #pragma unroll
  for (int i = 0; i < 4; i++){
    int s = rs + i*16;
    f32x4 v = *(const f32x4*)(Vb + (size_t)(s0 + s)*DIM + d0 + cd);
    tile[s][cd+0] = v[0]; tile[s][cd+1] = v[1];
    tile[s][cd+2] = v[2]; tile[s][cd+3] = v[3];
  }
  __syncthreads();
  int dl = t >> 4;
  int sl = (t & 15) * 4;
  #pragma unroll
  for (int i = 0; i < 4; i++){
    int d = dl + i*16;
    us4 h, l;
    #pragma unroll
    for (int j = 0; j < 4; j++){
      float x = tile[sl+j][d];
      u16 hh = f2bf(x);
      h[j] = hh;
      l[j] = f2bf(x - bf2f(hh));
    }
    size_t off = (size_t)(d0 + d) * (2*SEQ) + s0 + sl;
    *(us4*)(Vtb + off)       = h;
    *(us4*)(Vtb + off + SEQ) = l;
  }
}

// ---------- 256x256 8-wave 4-phase GEMM over VIRTUAL K (plain bf16 inner loop) ----
// Virtual K = 3 * 1024: g=vt>>4 selects {Ah.Bh, Al.Bh, Ah.Bl} via address offsets.
// LDS: [2 buf][ A 256x64 | B 256x64 ] = 128 KB. Halves wave-chunk-aligned:
//  A-mh half = rows {mh*64..+64} u {128+mh*64..+64}; B-nh = 4 chunks of 32.
// Phase: {ds_reads; stage 1 half (2 gloads); vmcnt(2); barrier; 16 MFMA}.
// fp32 C out (colwidth 1024). SPLITK: z=(kh<<3)|zb, contracts K-half kh.
template<int KROW, int SPLITK, int TX, int TY>
__global__ __launch_bounds__(512,1) void k8(const u16* __restrict__ A,
                                            const u16* __restrict__ B,
                                            float* __restrict__ C,
                                            size_t aStride, size_t bStride, size_t cStride){
  constexpr int LA = 2*KROW;
  constexpr int NT = 48;
  __shared__ __align__(16) u16 lds[2*32768];

  int xcd = blockIdx.x & 7;
  int idx = blockIdx.x >> 3;
  int nPerX = gridDim.x >> 3;
  int gid = xcd * nPerX + idx;
  constexpr int TPZ = TX*TY;
  int z  = gid / TPZ;
  int rm = gid % TPZ;
  int bx = rm % TX;
  int by = rm / TX;
  int zb = SPLITK ? (z & 7) : z;
  int kh = SPLITK ? (z >> 3) : 0;

  const u16* Ab = A + (size_t)zb * aStride + (size_t)kh * 1024;
  const u16* Bb = B + (size_t)zb * bStride + (size_t)kh * 1024;
  float* Cb = C + (size_t)z * cStride;

  int t0 = threadIdx.x, lane = t0 & 63, wv = t0 >> 6;
  int wm = (wv >> 2) * 128, wn = (wv & 3) * 64;
  int fr = lane & 15;
  int l3 = lane >> 3;
  int srcSlot = ((lane & 7) ^ l3) * 8;
  int rdS0 = ((0*4 + (lane >> 4)) ^ (lane & 7)) * 8;
  int rdS1 = ((1*4 + (lane >> 4)) ^ (lane & 7)) * 8;

  const u16* aB = Ab + (size_t)bx*256*LA + srcSlot;
  const u16* bB = Bb + (size_t)by*256*LA + srcSlot;

  f32x4 acc[8][4] = {};
  short8 aR[4][2], b0R[2][2], b1R[2][2];

  #define KOFF_A(vt) ((size_t)(((((vt)>>4)==1) ? KROW : 0) + ((vt)&15)*64))
  #define KOFF_B(vt) ((size_t)(((((vt)>>4)==2) ? KROW : 0) + ((vt)&15)*64))

  #define STAGE_A(bufb, vt, mh) { size_t ko = KOFF_A(vt);                      \
      _Pragma("unroll") for (int j = 0; j < 2; j++){                           \
        int c = j*8 + wv;                                                      \
        int row = (mh)*64 + (c>>3)*128 + (c&7)*8;                              \
        gload16(aB + (size_t)(row + l3)*LA + ko, &lds[(bufb) + row*64]); } }
  #define STAGE_B(bufb, vt, nh) { size_t ko = KOFF_B(vt);                      \
      _Pragma("unroll") for (int j = 0; j < 2; j++){                           \
        int c = j*8 + wv;                                                      \
        int row = (nh)*32 + (c>>2)*64 + (c&3)*8;                               \
        gload16(bB + (size_t)(row + l3)*LA + ko, &lds[(bufb) + 16384 + row*64]); } }

  #define LOAD_Af(bufb, mh) { _Pragma("unroll") for (int q = 0; q < 4; q++){   \
      int row = wm + (mh)*64 + q*16 + fr;                                      \
      aR[q][0] = *(const short8*)&lds[(bufb) + row*64 + rdS0];                 \
      aR[q][1] = *(const short8*)&lds[(bufb) + row*64 + rdS1]; } }
  #define LOAD_Bf(bufb, nh, BR) { _Pragma("unroll") for (int n = 0; n < 2; n++){ \
      int row = wn + (nh)*32 + n*16 + fr;                                      \
      BR[n][0] = *(const short8*)&lds[(bufb) + 16384 + row*64 + rdS0];         \
      BR[n][1] = *(const short8*)&lds[(bufb) + 16384 + row*64 + rdS1]; } }
  #define MFMA16(mh, nh, BR) { _Pragma("unroll") for (int q = 0; q < 4; q++){  \
      _Pragma("unroll") for (int n = 0; n < 2; n++){                           \
        f32x4 c0 = acc[(mh)*4+q][(nh)*2+n];                                    \
        c0 = __builtin_amdgcn_mfma_f32_16x16x32_bf16(aR[q][0], BR[n][0], c0, 0,0,0); \
        c0 = __builtin_amdgcn_mfma_f32_16x16x32_bf16(aR[q][1], BR[n][1], c0, 0,0,0); \
        acc[(mh)*4+q][(nh)*2+n] = c0; } } }

  #define PH_BAR() { __builtin_amdgcn_sched_barrier(0);                        \
                     __builtin_amdgcn_s_barrier();                             \
                     __builtin_amdgcn_sched_barrier(0); }
  #define PRIO_MFMA(mh, nh, BR) { __builtin_amdgcn_s_setprio(1);               \
      MFMA16(mh, nh, BR) __builtin_amdgcn_s_setprio(0); }

  // prologue: tile 0, all 4 halves, drain, barrier
  STAGE_A(0, 0, 0) STAGE_B(0, 0, 0) STAGE_B(0, 0, 1) STAGE_A(0, 0, 1)
  asm volatile("s_waitcnt vmcnt(0)" ::: "memory");
  PH_BAR();

  for (int t = 0; t < NT; t++){
    int bc = (t & 1) * 32768;
    int bs = bc ^ 32768;
    bool st = (t + 1 < NT);
    // phase 1: quad (0,0)
    LOAD_Af(bc, 0) LOAD_Bf(bc, 0, b0R)
    if (st){ STAGE_A(bs, t+1, 0) asm volatile("s_waitcnt vmcnt(2)" ::: "memory"); }
    else   { asm volatile("s_waitcnt vmcnt(1)" ::: "memory"); }
    PH_BAR();
    PRIO_MFMA(0, 0, b0R)
    // phase 2: quad (0,1)
    LOAD_Bf(bc, 1, b1R)
    if (st){ STAGE_B(bs, t+1, 0) asm volatile("s_waitcnt vmcnt(2)" ::: "memory"); }
    else   { asm volatile("s_waitcnt vmcnt(0)" ::: "memory"); }
    PH_BAR();
    PRIO_MFMA(0, 1, b1R)
    // phase 3: quad (1,1)
    LOAD_Af(bc, 1)
    if (st){ STAGE_B(bs, t+1, 1) asm volatile("s_waitcnt vmcnt(2)" ::: "memory"); }
    PH_BAR();
    PRIO_MFMA(1, 1, b1R)
    // phase 4: quad (1,0), no new reads
    if (st){ STAGE_A(bs, t+1, 1) asm volatile("s_waitcnt vmcnt(2)" ::: "memory"); }
    PH_BAR();
    PRIO_MFMA(1, 0, b0R)
    PH_BAR();
  }

  #undef KOFF_A
  #undef KOFF_B
  #undef STAGE_A
  #undef STAGE_B
  #undef LOAD_Af
  #undef LOAD_Bf
  #undef MFMA16
  #undef PH_BAR
  #undef PRIO_MFMA

  int cr = (lane >> 4) * 4;
  #pragma unroll
  for (int mi = 0; mi < 8; mi++){
    int gr = bx*256 + wm + (mi >> 2)*64 + (mi & 3)*16 + cr;
    #pragma unroll
    for (int ni = 0; ni < 4; ni++){
      int gc = by*256 + wn + (ni >> 1)*32 + (ni & 1)*16 + fr;
      #pragma unroll
      for (int e = 0; e < 4; e++)
        Cb[(size_t)(gr + e) * 1024 + gc] = acc[mi][ni][e];
    }
  }
}

// ---------- reduce split-K partials + scale + split to u16 [hi|lo] ----------
__global__ __launch_bounds__(256) void k_reduce_split(const float* __restrict__ P,
                                                      u16* __restrict__ Ws){
  int i = blockIdx.x*256 + threadIdx.x;
  int rg = i >> 8;                 // zb*1024 + d
  int c  = (i & 255) * 4;
  f32x4 a = *(const f32x4*)(P + (size_t)rg*1024 + c);
  f32x4 b = *(const f32x4*)(P + ((size_t)rg + 8192)*1024 + c);
  us4 h, l;
  #pragma unroll
  for (int j = 0; j < 4; j++){
    float x = (a[j] + b[j]) * 0.03125f;
    u16 hh = f2bf(x);
    h[j] = hh;
    l[j] = f2bf(x - bf2f(hh));
  }
  int zb = rg >> 10, d = rg & 1023;
  u16* Wb = Ws + (size_t)zb * ((size_t)DIM * 2*DIM);
  *(us4*)(Wb + (size_t)d*2048 + c)        = h;
  *(us4*)(Wb + (size_t)d*2048 + 1024 + c) = l;
}

// ---------- legacy 128x128 2-barrier GEMM (fallback tiers, verified R10) ----------
template<int KROW, int SPLITK, int SPLITOUT, int NOUT, int TX, int TY>
__global__ __launch_bounds__(256,4) void k_gemmS(const u16* __restrict__ A,
                                                 const u16* __restrict__ B,
                                                 void* __restrict__ Cout,
                                                 size_t aStride, size_t bStride, size_t cStride){
  constexpr int LA = 2*KROW;
  constexpr int ITER = (SPLITK ? 1024 : KROW) / 32;
  __shared__ __align__(16) u16 lds[4][128*32];

  int xcd = blockIdx.x & 7;
  int idx = blockIdx.x >> 3;
  int nPerX = gridDim.x >> 3;
  int gid = xcd * nPerX + idx;
  constexpr int TPZ = TX*TY;
  int z  = gid / TPZ;
  int rm = gid % TPZ;
  int bx = rm % TX;
  int by = rm / TX;
  int zb = SPLITK ? (z & 7) : z;
  int kh = SPLITK ? (z >> 3) : 0;

  const u16* Ab = A + (size_t)zb * aStride + (size_t)kh * 1024;
  const u16* Bb = B + (size_t)zb * bStride + (size_t)kh * 1024;

  int t = threadIdx.x, lane = t & 63, w = t >> 6;
  int wm = (w & 1) * 64, wn = (w >> 1) * 64;
  int fr = lane & 15;
  int srow    = lane >> 2;
  int srcSlot = ((lane & 3) ^ ((lane >> 3) & 3)) * 8;

  const u16* aBase = Ab + ((size_t)bx*128) * LA + srcSlot;
  const u16* bBase = Bb + ((size_t)by*128) * LA + srcSlot;
  int rdSlot = (((lane >> 4) ^ ((fr >> 1) & 3))) * 8;

  f32x4 acc[4][4] = {};

  for (int ti = 0; ti < ITER; ti++){
    size_t kof = (size_t)ti * 32;
    #pragma unroll
    for (int o = 0; o < 2; o++){
      int c = w*2 + o;
      size_t ro = (size_t)(c*16 + srow) * LA + kof;
      const u16* ga = aBase + ro;
      const u16* gb = bBase + ro;
      int le = c * 512;
      gload16(ga,        &lds[0][le]);
      gload16(ga + KROW, &lds[1][le]);
      gload16(gb,        &lds[2][le]);
      gload16(gb + KROW, &lds[3][le]);
    }
    __syncthreads();

    short8 fah[4], fal[4], fbh[4], fbl[4];
    #pragma unroll
    for (int mi = 0; mi < 4; mi++){
      fah[mi] = *(const short8*)&lds[0][(wm + mi*16 + fr)*32 + rdSlot];
      fal[mi] = *(const short8*)&lds[1][(wm + mi*16 + fr)*32 + rdSlot];
      fbh[mi] = *(const short8*)&lds[2][(wn + mi*16 + fr)*32 + rdSlot];
      fbl[mi] = *(const short8*)&lds[3][(wn + mi*16 + fr)*32 + rdSlot];
    }
    #pragma unroll
    for (int mi = 0; mi < 4; mi++){
      #pragma unroll
      for (int ni = 0; ni < 4; ni++){
        acc[mi][ni] = __builtin_amdgcn_mfma_f32_16x16x32_bf16(fah[mi], fbh[ni], acc[mi][ni], 0,0,0);
        acc[mi][ni] = __builtin_amdgcn_mfma_f32_16x16x32_bf16(fah[mi], fbl[ni], acc[mi][ni], 0,0,0);
        acc[mi][ni] = __builtin_amdgcn_mfma_f32_16x16x32_bf16(fal[mi], fbh[ni], acc[mi][ni], 0,0,0);
      }
    }
    __syncthreads();
  }

  int cr = (lane >> 4) * 4, cc = lane & 15;
  if (SPLITOUT){
    u16* Cb = (u16*)Cout + (size_t)z * cStride;
    const float scale = 0.03125f;
    #pragma unroll
    for (int mi = 0; mi < 4; mi++){
      int gr = bx*128 + wm + mi*16 + cr;
      #pragma unroll
      for (int ni = 0; ni < 4; ni++){
        int gc = by*128 + wn + ni*16 + cc;
        #pragma unroll
        for (int rr = 0; rr < 4; rr++){
          float x = acc[mi][ni][rr] * scale;
          u16 h = f2bf(x);
          u16 l = f2bf(x - bf2f(h));
          size_t off = (size_t)(gr + rr) * (2*NOUT) + gc;
          Cb[off]        = h;
          Cb[off + NOUT] = l;
        }
      }
    }
  } else {
    float* Cb = (float*)Cout + (size_t)z * cStride;
    #pragma unroll
    for (int mi = 0; mi < 4; mi++){
      int gr = bx*128 + wm + mi*16 + cr;
      #pragma unroll
      for (int ni = 0; ni < 4; ni++){
        int gc = by*128 + wn + ni*16 + cc;
        #pragma unroll
        for (int rr = 0; rr < 4; rr++){
          Cb[(size_t)(gr + rr) * NOUT + gc] = acc[mi][ni][rr];
        }
      }
    }
  }
}

// ---------- row softmax over D=1024, in place on d_out ----------
__global__ __launch_bounds__(256) void k_softmax(float* __restrict__ O){
  float* p = O + (size_t)blockIdx.x * DIM;
  int t = threadIdx.x;
  int lane = t & 63, wave = t >> 6;
  f32x4 v = *(f32x4*)(p + t*4);
  float m = fmaxf(fmaxf(v[0], v[1]), fmaxf(v[2], v[3]));
  #pragma unroll
  for (int o = 32; o > 0; o >>= 1) m = fmaxf(m, __shfl_xor(m, o));
  __shared__ float rmax[4], rsum[4];
  if (lane == 0) rmax[wave] = m;
  __syncthreads();
  m = fmaxf(fmaxf(rmax[0], rmax[1]), fmaxf(rmax[2], rmax[3]));
  float e0 = expf(v[0]-m), e1 = expf(v[1]-m), e2 = expf(v[2]-m), e3 = expf(v[3]-m);
  float s = e0 + e1 + e2 + e3;
  #pragma unroll
  for (int o = 32; o > 0; o >>= 1) s += __shfl_xor(s, o);
  if (lane == 0) rsum[wave] = s;
  __syncthreads();
  s = rsum[0] + rsum[1] + rsum[2] + rsum[3];
  float inv = 1.0f / s;
  f32x4 rv = { e0*inv, e1*inv, e2*inv, e3*inv };
  *(f32x4*)(p + t*4) = rv;
}

extern "C" void kernel_launch(void* const* d_in, const int* in_sizes, int n_in,
                              void* d_out, int out_size, void* d_ws, size_t ws_size,
                              hipStream_t stream){
  const float* Q = (const float*)d_in[0];
  const float* K = (const float*)d_in[1];
  const float* V = (const float*)d_in[2];
  float* Out = (float*)d_out;
  u16* w = (u16*)d_ws;

  const size_t QsB = (size_t)SEQ * (2*DIM);
  const size_t KtB = (size_t)DIM * (2*SEQ);
  const size_t VtB = KtB;
  const size_t WsB = (size_t)DIM * (2*DIM);

  dim3 blk(256);
  dim3 cgrid(SEQ/64, DIM/64, 16);

  const size_t base2 = 8 * (KtB + VtB + WsB) * sizeof(u16);          // ~167.8 MB
  const size_t needA = base2 + (size_t)16*1024*1024*sizeof(float);   // ~234.9 MB
  const size_t needB = base2;

  if (ws_size >= needA){
    u16* Kt = w;
    u16* Vt = Kt + 8*KtB;
    u16* Ws = Vt + 8*VtB;
    float* Part = (float*)(Ws + 8*WsB);
    u16* Qs = w;                         // reuses Kt/Vt region after GEMM-A (stream-ordered)
    k_convert_kv<<<cgrid, blk, 0, stream>>>(K, V, Kt, Vt);
    // GEMM-A (8-phase, virtual-K, split-K x2): Part[z=kh*8+zb] = Vt_zb . Kt_zb^T |_khalf
    k8<SEQ, 1, 4, 4><<<dim3(256), dim3(512), 0, stream>>>(
        Vt, Kt, Part, VtB, KtB, (size_t)1024*1024);
    k_reduce_split<<<dim3(8192), blk, 0, stream>>>(Part, Ws);
    k_split<<<dim3(2048), blk, 0, stream>>>(Q, Qs, 8*SEQ*(DIM/4));
    // GEMM-B (8-phase, virtual-K): Out = Qs . Ws^T
    k8<DIM, 0, 8, 4><<<dim3(256), dim3(512), 0, stream>>>(
        Qs, Ws, Out, QsB, WsB, (size_t)SEQ*DIM);
  } else if (ws_size >= needB){
    u16* Kt = w;
    u16* Vt = Kt + 8*KtB;
    u16* Ws = Vt + 8*VtB;
    u16* Qs = w;
    k_convert_kv<<<cgrid, blk, 0, stream>>>(K, V, Kt, Vt);
    k_gemmS<SEQ, 0, 1, DIM, 8, 8><<<dim3(512), blk, 0, stream>>>(
        Vt, Kt, Ws, VtB, KtB, WsB);
    k_split<<<dim3(2048), blk, 0, stream>>>(Q, Qs, 8*SEQ*(DIM/4));
    k_gemmS<DIM, 0, 0, DIM, 16, 8><<<dim3(1024), blk, 0, stream>>>(
        Qs, Ws, Out, QsB, WsB, (size_t)SEQ*DIM);
  } else {
    // per-batch fallback
    u16* Qs = w;
    u16* Kt = Qs + QsB;
    u16* Vt = Kt + KtB;
    u16* Ws = Vt + VtB;
    for (int b = 0; b < BATCH; b++){
      const size_t inOff = (size_t)b * SEQ * DIM;
      k_split<<<dim3(1024), blk, 0, stream>>>(Q + inOff, Qs, SEQ*(DIM/4));
      k_convert_kv<<<dim3(SEQ/64, DIM/64, 1), blk, 0, stream>>>(K + inOff, K + inOff, Kt, Kt);
      k_convert_kv<<<dim3(SEQ/64, DIM/64, 1), blk, 0, stream>>>(V + inOff, V + inOff, Vt, Vt);
      k_gemmS<SEQ, 0, 1, DIM, 8, 8><<<dim3(64), blk, 0, stream>>>(
          Vt, Kt, Ws, VtB, KtB, WsB);
      k_gemmS<DIM, 0, 0, DIM, 16, 8><<<dim3(128), blk, 0, stream>>>(
          Qs, Ws, Out + inOff, QsB, WsB, (size_t)SEQ*DIM);
    }
  }
  k_softmax<<<dim3(BATCH*SEQ), blk, 0, stream>>>(Out);
}

// Round 12
// 295.845 us; speedup vs baseline: 1.0602x; 1.0047x over previous
//
#include <hip/hip_runtime.h>
#include <hip/hip_bf16.h>
#include <stdint.h>

#define BATCH 8
#define SEQ   2048
#define DIM   1024

typedef unsigned short u16;
typedef __attribute__((ext_vector_type(8))) short short8;
typedef __attribute__((ext_vector_type(4))) float f32x4;
typedef __attribute__((ext_vector_type(4))) unsigned short us4;

__device__ __forceinline__ u16 f2bf(float x){
  union { float f; uint32_t u; } c; c.f = x;
  uint32_t u = c.u;
  uint32_t r = u + 0x7fffu + ((u >> 16) & 1u);
  return (u16)(r >> 16);
}
__device__ __forceinline__ float bf2f(u16 s){
  union { uint32_t u; float f; } c; c.u = ((uint32_t)s) << 16;
  return c.f;
}

__device__ __forceinline__ void gload16(const void* g, void* l){
  __builtin_amdgcn_global_load_lds(
      (const __attribute__((address_space(1))) void*)g,
      (__attribute__((address_space(3))) void*)l, 16, 0, 0);
}

// ---------- split fp32 [R][1024] -> u16 [R][2048] rows packed [hi|lo] ----------
__global__ __launch_bounds__(256) void k_split(const float* __restrict__ src,
                                               u16* __restrict__ dst, int nchunk){
  for (int i = blockIdx.x*blockDim.x + threadIdx.x; i < nchunk; i += gridDim.x*blockDim.x){
    int r = i >> 8;
    int c = (i & 255) << 2;
    f32x4 v = *(const f32x4*)(src + (size_t)r*DIM + c);
    us4 h, l;
    #pragma unroll
    for (int j = 0; j < 4; j++){
      u16 hh = f2bf(v[j]);
      h[j] = hh;
      l[j] = f2bf(v[j] - bf2f(hh));
    }
    u16* d = dst + (size_t)r*(2*DIM) + c;
    *(us4*)d         = h;
    *(us4*)(d + DIM) = l;
  }
}

// ---------- transpose + split (K and V in one launch): z<8 -> K->Kt, z>=8 -> V->Vt ----------
__global__ __launch_bounds__(256) void k_convert_kv(const float* __restrict__ K,
                                                    const float* __restrict__ V,
                                                    u16* __restrict__ Kt,
                                                    u16* __restrict__ Vt){
  __shared__ float tile[64][65];
  int z = blockIdx.z;
  const float* Src = (z < 8 ? K : V);
  u16* Dst = (z < 8 ? Kt : Vt);
  int zb = z & 7;
  const float* Vb = Src + (size_t)zb * SEQ * DIM;
  u16* Vtb = Dst + (size_t)zb * DIM * (2*SEQ);
  int s0 = blockIdx.x * 64, d0 = blockIdx.y * 64;
  int t = threadIdx.x;
  int rs = t >> 4;
  int cd = (t & 15) * 4;
  #pragma unroll
  for (int i = 0; i < 4; i++){
    int s = rs + i*16;
    f32x4 v = *(const f32x4*)(Vb + (size_t)(s0 + s)*DIM + d0 + cd);
    tile[s][cd+0] = v[0]; tile[s][cd+1] = v[1];
    tile[s][cd+2] = v[2]; tile[s][cd+3] = v[3];
  }
  __syncthreads();
  int dl = t >> 4;
  int sl = (t & 15) * 4;
  #pragma unroll
  for (int i = 0; i < 4; i++){
    int d = dl + i*16;
    us4 h, l;
    #pragma unroll
    for (int j = 0; j < 4; j++){
      float x = tile[sl+j][d];
      u16 hh = f2bf(x);
      h[j] = hh;
      l[j] = f2bf(x - bf2f(hh));
    }
    size_t off = (size_t)(d0 + d) * (2*SEQ) + s0 + sl;
    *(us4*)(Vtb + off)       = h;
    *(us4*)(Vtb + off + SEQ) = l;
  }
}

// ---------- 256x256 8-wave GEMM, virtual-K, 4-slot depth-2 pipeline ----------
// Virtual K = 3*1024 over vK=32 tiles (NT=96): g=vt>>5 selects {Ah.Bh, Al.Bh, Ah.Bl}.
// LDS: 4 slots x (A 256x32 | B 256x32) = 128 KB. ONE barrier per tile; free-running
// waves inside (compiler fine-lgkmcnt overlaps ds_read with MFMA). Prefetch dist 2,
// counted vmcnt(4) certifies tile t+1 before the tile-boundary barrier.
// SPLITK: z=(kh<<3)|zb contracts K-half kh. fp32 C out, ld=1024.
template<int KROW, int SPLITK, int TX, int TY>
__global__ __launch_bounds__(512,1) void k8(const u16* __restrict__ A,
                                            const u16* __restrict__ B,
                                            float* __restrict__ C,
                                            size_t aStride, size_t bStride, size_t cStride){
  constexpr int LA = 2*KROW;
  constexpr int NT = 96;
  __shared__ __align__(16) u16 lds[4*16384];   // 4 slots x 32 KB

  int xcd = blockIdx.x & 7;
  int idx = blockIdx.x >> 3;
  int nPerX = gridDim.x >> 3;
  int gid = xcd * nPerX + idx;
  constexpr int TPZ = TX*TY;
  int z  = gid / TPZ;
  int rm = gid % TPZ;
  int bx = rm % TX;
  int by = rm / TX;
  int zb = SPLITK ? (z & 7) : z;
  int kh = SPLITK ? (z >> 3) : 0;

  const u16* Ab = A + (size_t)zb * aStride + (size_t)kh * 1024;
  const u16* Bb = B + (size_t)zb * bStride + (size_t)kh * 1024;
  float* Cb = C + (size_t)z * cStride;

  int t0 = threadIdx.x, lane = t0 & 63, wv = t0 >> 6;
  int wm = (wv >> 2) * 128, wn = (wv & 3) * 64;
  int fr = lane & 15;
  int rdSlot  = ((lane >> 4) ^ ((fr >> 1) & 3)) * 8;
  int srcSlot = ((lane & 3) ^ ((lane >> 3) & 3)) * 8;
  int l2 = lane >> 2;                        // 0..15: row within 16-row chunk

  const u16* aB = Ab + (size_t)bx*256*LA + srcSlot;
  const u16* bB = Bb + (size_t)by*256*LA + srcSlot;

  f32x4 acc[8][4] = {};
  short8 aR[4], bR[4];

  // koff of virtual tile vt for A / B streams
  #define KOFF_A(vt) ((size_t)((((vt)>>5)==1 ? KROW : 0) + ((vt)&31)*32))
  #define KOFF_B(vt) ((size_t)((((vt)>>5)==2 ? KROW : 0) + ((vt)&31)*32))

  // stage A (16 KB = 2 gloads/thread) of tile vt into slot sl
  #define STAGE_A(sl, vt) { size_t ko = KOFF_A(vt);                            \
      _Pragma("unroll") for (int j = 0; j < 2; j++){                           \
        int rr = j*128 + wv*16 + l2;                                           \
        gload16(aB + (size_t)rr*LA + ko, &lds[(sl)*16384 + j*4096 + wv*512]);  \
      } }
  #define STAGE_B(sl, vt) { size_t ko = KOFF_B(vt);                            \
      _Pragma("unroll") for (int j = 0; j < 2; j++){                           \
        int rr = j*128 + wv*16 + l2;                                           \
        gload16(bB + (size_t)rr*LA + ko, &lds[(sl)*16384 + 8192 + j*4096 + wv*512]); \
      } }

  #define LOAD_A4(sl, h) { _Pragma("unroll") for (int q = 0; q < 4; q++){      \
      int row = wm + ((h)*4+q)*16 + fr;                                        \
      aR[q] = *(const short8*)&lds[(sl)*16384 + row*32 + rdSlot]; } }
  #define LOAD_B4(sl) { _Pragma("unroll") for (int n = 0; n < 4; n++){         \
      int row = wn + n*16 + fr;                                                \
      bR[n] = *(const short8*)&lds[(sl)*16384 + 8192 + row*32 + rdSlot]; } }
  #define MFMA16(h) { _Pragma("unroll") for (int q = 0; q < 4; q++){           \
      _Pragma("unroll") for (int n = 0; n < 4; n++){                           \
        acc[(h)*4+q][n] = __builtin_amdgcn_mfma_f32_16x16x32_bf16(             \
            aR[q], bR[n], acc[(h)*4+q][n], 0,0,0); } } }

  // prologue: stage tiles 0 and 1, certify tile 0
  STAGE_A(0, 0) STAGE_B(0, 0)
  STAGE_A(1, 1) STAGE_B(1, 1)
  asm volatile("s_waitcnt vmcnt(4)" ::: "memory");
  __builtin_amdgcn_sched_barrier(0);
  __builtin_amdgcn_s_barrier();

  for (int t = 0; t < NT; t++){
    int sl = t & 3;
    int st = t + 2;
    int ss = st & 3;
    // cluster 1
    LOAD_A4(sl, 0)
    LOAD_B4(sl)
    if (st < NT) STAGE_A(ss, st)
    __builtin_amdgcn_s_setprio(1);
    MFMA16(0)
    __builtin_amdgcn_s_setprio(0);
    // cluster 2 (bR reused from registers)
    LOAD_A4(sl, 1)
    if (st < NT) STAGE_B(ss, st)
    __builtin_amdgcn_s_setprio(1);
    MFMA16(1)
    __builtin_amdgcn_s_setprio(0);
    // tile boundary: certify t+1, sync
    __builtin_amdgcn_sched_barrier(0);
    if (t < NT-2){ asm volatile("s_waitcnt vmcnt(4)" ::: "memory"); }
    else         { asm volatile("s_waitcnt vmcnt(0)" ::: "memory"); }
    __builtin_amdgcn_sched_barrier(0);
    __builtin_amdgcn_s_barrier();
    __builtin_amdgcn_sched_barrier(0);
  }

  #undef KOFF_A
  #undef KOFF_B
  #undef STAGE_A
  #undef STAGE_B
  #undef LOAD_A4
  #undef LOAD_B4
  #undef MFMA16

  int cr = (lane >> 4) * 4;
  #pragma unroll
  for (int mi = 0; mi < 8; mi++){
    int gr = bx*256 + wm + mi*16 + cr;
    #pragma unroll
    for (int ni = 0; ni < 4; ni++){
      int gc = by*256 + wn + ni*16 + fr;
      #pragma unroll
      for (int e = 0; e < 4; e++)
        Cb[(size_t)(gr + e) * 1024 + gc] = acc[mi][ni][e];
    }
  }
}

// ---------- reduce split-K partials + scale + split to u16 [hi|lo] ----------
__global__ __launch_bounds__(256) void k_reduce_split(const float* __restrict__ P,
                                                      u16* __restrict__ Ws){
  int i = blockIdx.x*256 + threadIdx.x;
  int rg = i >> 8;                 // zb*1024 + d
  int c  = (i & 255) * 4;
  f32x4 a = *(const f32x4*)(P + (size_t)rg*1024 + c);
  f32x4 b = *(const f32x4*)(P + ((size_t)rg + 8192)*1024 + c);
  us4 h, l;
  #pragma unroll
  for (int j = 0; j < 4; j++){
    float x = (a[j] + b[j]) * 0.03125f;
    u16 hh = f2bf(x);
    h[j] = hh;
    l[j] = f2bf(x - bf2f(hh));
  }
  int zb = rg >> 10, d = rg & 1023;
  u16* Wb = Ws + (size_t)zb * ((size_t)DIM * 2*DIM);
  *(us4*)(Wb + (size_t)d*2048 + c)        = h;
  *(us4*)(Wb + (size_t)d*2048 + 1024 + c) = l;
}

// ---------- legacy 128x128 2-barrier GEMM (fallback tiers, verified R10) ----------
template<int KROW, int SPLITK, int SPLITOUT, int NOUT, int TX, int TY>
__global__ __launch_bounds__(256,4) void k_gemmS(const u16* __restrict__ A,
                                                 const u16* __restrict__ B,
                                                 void* __restrict__ Cout,
                                                 size_t aStride, size_t bStride, size_t cStride){
  constexpr int LA = 2*KROW;
  constexpr int ITER = (SPLITK ? 1024 : KROW) / 32;
  __shared__ __align__(16) u16 lds[4][128*32];

  int xcd = blockIdx.x & 7;
  int idx = blockIdx.x >> 3;
  int nPerX = gridDim.x >> 3;
  int gid = xcd * nPerX + idx;
  constexpr int TPZ = TX*TY;
  int z  = gid / TPZ;
  int rm = gid % TPZ;
  int bx = rm % TX;
  int by = rm / TX;
  int zb = SPLITK ? (z & 7) : z;
  int kh = SPLITK ? (z >> 3) : 0;

  const u16* Ab = A + (size_t)zb * aStride + (size_t)kh * 1024;
  const u16* Bb = B + (size_t)zb * bStride + (size_t)kh * 1024;

  int t = threadIdx.x, lane = t & 63, w = t >> 6;
  int wm = (w & 1) * 64, wn = (w >> 1) * 64;
  int fr = lane & 15;
  int srow    = lane >> 2;
  int srcSlot = ((lane & 3) ^ ((lane >> 3) & 3)) * 8;

  const u16* aBase = Ab + ((size_t)bx*128) * LA + srcSlot;
  const u16* bBase = Bb + ((size_t)by*128) * LA + srcSlot;
  int rdSlot = (((lane >> 4) ^ ((fr >> 1) & 3))) * 8;

  f32x4 acc[4][4] = {};

  for (int ti = 0; ti < ITER; ti++){
    size_t kof = (size_t)ti * 32;
    #pragma unroll
    for (int o = 0; o < 2; o++){
      int c = w*2 + o;
      size_t ro = (size_t)(c*16 + srow) * LA + kof;
      const u16* ga = aBase + ro;
      const u16* gb = bBase + ro;
      int le = c * 512;
      gload16(ga,        &lds[0][le]);
      gload16(ga + KROW, &lds[1][le]);
      gload16(gb,        &lds[2][le]);
      gload16(gb + KROW, &lds[3][le]);
    }
    __syncthreads();

    short8 fah[4], fal[4], fbh[4], fbl[4];
    #pragma unroll
    for (int mi = 0; mi < 4; mi++){
      fah[mi] = *(const short8*)&lds[0][(wm + mi*16 + fr)*32 + rdSlot];
      fal[mi] = *(const short8*)&lds[1][(wm + mi*16 + fr)*32 + rdSlot];
      fbh[mi] = *(const short8*)&lds[2][(wn + mi*16 + fr)*32 + rdSlot];
      fbl[mi] = *(const short8*)&lds[3][(wn + mi*16 + fr)*32 + rdSlot];
    }
    #pragma unroll
    for (int mi = 0; mi < 4; mi++){
      #pragma unroll
      for (int ni = 0; ni < 4; ni++){
        acc[mi][ni] = __builtin_amdgcn_mfma_f32_16x16x32_bf16(fah[mi], fbh[ni], acc[mi][ni], 0,0,0);
        acc[mi][ni] = __builtin_amdgcn_mfma_f32_16x16x32_bf16(fah[mi], fbl[ni], acc[mi][ni], 0,0,0);
        acc[mi][ni] = __builtin_amdgcn_mfma_f32_16x16x32_bf16(fal[mi], fbh[ni], acc[mi][ni], 0,0,0);
      }
    }
    __syncthreads();
  }

  int cr = (lane >> 4) * 4, cc = lane & 15;
  if (SPLITOUT){
    u16* Cb = (u16*)Cout + (size_t)z * cStride;
    const float scale = 0.03125f;
    #pragma unroll
    for (int mi = 0; mi < 4; mi++){
      int gr = bx*128 + wm + mi*16 + cr;
      #pragma unroll
      for (int ni = 0; ni < 4; ni++){
        int gc = by*128 + wn + ni*16 + cc;
        #pragma unroll
        for (int rr = 0; rr < 4; rr++){
          float x = acc[mi][ni][rr] * scale;
          u16 h = f2bf(x);
          u16 l = f2bf(x - bf2f(h));
          size_t off = (size_t)(gr + rr) * (2*NOUT) + gc;
          Cb[off]        = h;
          Cb[off + NOUT] = l;
        }
      }
    }
  } else {
    float* Cb = (float*)Cout + (size_t)z * cStride;
    #pragma unroll
    for (int mi = 0; mi < 4; mi++){
      int gr = bx*128 + wm + mi*16 + cr;
      #pragma unroll
      for (int ni = 0; ni < 4; ni++){
        int gc = by*128 + wn + ni*16 + cc;
        #pragma unroll
        for (int rr = 0; rr < 4; rr++){
          Cb[(size_t)(gr + rr) * NOUT + gc] = acc[mi][ni][rr];
        }
      }
    }
  }
}

// ---------- row softmax over D=1024, in place on d_out ----------
__global__ __launch_bounds__(256) void k_softmax(float* __restrict__ O){
  float* p = O + (size_t)blockIdx.x * DIM;
  int t = threadIdx.x;
  int lane = t & 63, wave = t >> 6;
  f32x4 v = *(f32x4*)(p + t*4);
  float m = fmaxf(fmaxf(v[0], v[1]), fmaxf(v[2], v[3]));
  #pragma unroll
  for (int o = 32; o > 0; o >>= 1) m = fmaxf(m, __shfl_xor(m, o));
  __shared__ float rmax[4], rsum[4];
  if (lane == 0) rmax[wave] = m;
  __syncthreads();
  m = fmaxf(fmaxf(rmax[0], rmax[1]), fmaxf(rmax[2], rmax[3]));
  float e0 = expf(v[0]-m), e1 = expf(v[1]-m), e2 = expf(v[2]-m), e3 = expf(v[3]-m);
  float s = e0 + e1 + e2 + e3;
  #pragma unroll
  for (int o = 32; o > 0; o >>= 1) s += __shfl_xor(s, o);
  if (lane == 0) rsum[wave] = s;
  __syncthreads();
  s = rsum[0] + rsum[1] + rsum[2] + rsum[3];
  float inv = 1.0f / s;
  f32x4 rv = { e0*inv, e1*inv, e2*inv, e3*inv };
  *(f32x4*)(p + t*4) = rv;
}

extern "C" void kernel_launch(void* const* d_in, const int* in_sizes, int n_in,
                              void* d_out, int out_size, void* d_ws, size_t ws_size,
                              hipStream_t stream){
  const float* Q = (const float*)d_in[0];
  const float* K = (const float*)d_in[1];
  const float* V = (const float*)d_in[2];
  float* Out = (float*)d_out;
  u16* w = (u16*)d_ws;

  const size_t QsB = (size_t)SEQ * (2*DIM);
  const size_t KtB = (size_t)DIM * (2*SEQ);
  const size_t VtB = KtB;
  const size_t WsB = (size_t)DIM * (2*DIM);

  dim3 blk(256);
  dim3 cgrid(SEQ/64, DIM/64, 16);

  const size_t base2 = 8 * (KtB + VtB + WsB) * sizeof(u16);          // ~167.8 MB
  const size_t needA = base2 + (size_t)16*1024*1024*sizeof(float);   // ~234.9 MB
  const size_t needB = base2;

  if (ws_size >= needA){
    u16* Kt = w;
    u16* Vt = Kt + 8*KtB;
    u16* Ws = Vt + 8*VtB;
    float* Part = (float*)(Ws + 8*WsB);
    u16* Qs = w;                         // reuses Kt/Vt region after GEMM-A (stream-ordered)
    k_convert_kv<<<cgrid, blk, 0, stream>>>(K, V, Kt, Vt);
    // GEMM-A (virtual-K pipeline, split-K x2): Part[z=kh*8+zb] = Vt_zb . Kt_zb^T |_khalf
    k8<SEQ, 1, 4, 4><<<dim3(256), dim3(512), 0, stream>>>(
        Vt, Kt, Part, VtB, KtB, (size_t)1024*1024);
    k_reduce_split<<<dim3(8192), blk, 0, stream>>>(Part, Ws);
    k_split<<<dim3(2048), blk, 0, stream>>>(Q, Qs, 8*SEQ*(DIM/4));
    // GEMM-B (virtual-K pipeline): Out = Qs . Ws^T
    k8<DIM, 0, 8, 4><<<dim3(256), dim3(512), 0, stream>>>(
        Qs, Ws, Out, QsB, WsB, (size_t)SEQ*DIM);
  } else if (ws_size >= needB){
    u16* Kt = w;
    u16* Vt = Kt + 8*KtB;
    u16* Ws = Vt + 8*VtB;
    u16* Qs = w;
    k_convert_kv<<<cgrid, blk, 0, stream>>>(K, V, Kt, Vt);
    k_gemmS<SEQ, 0, 1, DIM, 8, 8><<<dim3(512), blk, 0, stream>>>(
        Vt, Kt, Ws, VtB, KtB, WsB);
    k_split<<<dim3(2048), blk, 0, stream>>>(Q, Qs, 8*SEQ*(DIM/4));
    k_gemmS<DIM, 0, 0, DIM, 16, 8><<<dim3(1024), blk, 0, stream>>>(
        Qs, Ws, Out, QsB, WsB, (size_t)SEQ*DIM);
  } else {
    // per-batch fallback
    u16* Qs = w;
    u16* Kt = Qs + QsB;
    u16* Vt = Kt + KtB;
    u16* Ws = Vt + VtB;
    for (int b = 0; b < BATCH; b++){
      const size_t inOff = (size_t)b * SEQ * DIM;
      k_split<<<dim3(1024), blk, 0, stream>>>(Q + inOff, Qs, SEQ*(DIM/4));
      k_convert_kv<<<dim3(SEQ/64, DIM/64, 1), blk, 0, stream>>>(K + inOff, K + inOff, Kt, Kt);
      k_convert_kv<<<dim3(SEQ/64, DIM/64, 1), blk, 0, stream>>>(V + inOff, V + inOff, Vt, Vt);
      k_gemmS<SEQ, 0, 1, DIM, 8, 8><<<dim3(64), blk, 0, stream>>>(
          Vt, Kt, Ws, VtB, KtB, WsB);
      k_gemmS<DIM, 0, 0, DIM, 16, 8><<<dim3(128), blk, 0, stream>>>(
          Qs, Ws, Out + inOff, QsB, WsB, (size_t)SEQ*DIM);
    }
  }
  k_softmax<<<dim3(BATCH*SEQ), blk, 0, stream>>>(Out);
}